// Round 2
// baseline (97.995 us; speedup 1.0000x reference)
//
#include <hip/hip_runtime.h>
#include <hip/hip_bf16.h>

// Problem constants (from reference)
#define SS 4096   // num_samples
#define DD 128    // embed_dim
#define PP 64     // num_proxies
#define NH 2      // heads
#define HDIM 64   // head dim

typedef unsigned short u16;
typedef __attribute__((ext_vector_type(8))) short short8;   // 8 bf16 in 4 VGPRs
typedef __attribute__((ext_vector_type(4))) float float4v;  // MFMA accumulator

__device__ inline float bf2f(u16 u) {
    union { unsigned int i; float f; } v; v.i = ((unsigned int)u) << 16; return v.f;
}
__device__ inline u16 f2bf(float f) {
    union { float f; unsigned int i; } v; v.f = f;
    unsigned int i = v.i;
    return (u16)((i + 0x7fffu + ((i >> 16) & 1u)) >> 16);  // RNE
}

// ---------------------------------------------------------------------------
// Runtime input-dtype detection (wave-uniform, deterministic).
// fp32 data read as u16 pairs: low half-words have uniform-random exponent
// fields -> ~25% of words have bf16-exponent >= 0xBF (|v| >= 2^64).
// True bf16 N(0,1)-scale tensors never do. 256 words scanned -> miss
// probability ~0.75^128 ~ 1e-16.
// ---------------------------------------------------------------------------
__device__ inline bool detect_f32(const void* raw) {
    const u16* w = (const u16*)raw;
    const int lane = threadIdx.x & 63;
    bool hit = false;
    #pragma unroll
    for (int j = 0; j < 4; ++j) {
        u16 x = w[lane * 4 + j];
        int e = (x >> 7) & 0xFF;
        hit |= (e >= 0xBF);
    }
    return __ballot(hit) != 0ull;
}

// dtype-generic loads/stores -------------------------------------------------
template<bool F32>
__device__ inline float lds1(const void* p, int idx) {
    if constexpr (F32) return ((const float*)p)[idx];
    else               return bf2f(((const u16*)p)[idx]);
}

template<bool F32>
__device__ inline short8 ld8(const void* p, int idx) {  // 8 consecutive elems -> bf16 frag
    if constexpr (!F32) {
        return *(const short8*)((const u16*)p + idx);
    } else {
        const float* f = (const float*)p + idx;
        float4 a = *(const float4*)f;
        float4 b = *(const float4*)(f + 4);
        short8 r;
        r[0] = (short)f2bf(a.x); r[1] = (short)f2bf(a.y);
        r[2] = (short)f2bf(a.z); r[3] = (short)f2bf(a.w);
        r[4] = (short)f2bf(b.x); r[5] = (short)f2bf(b.y);
        r[6] = (short)f2bf(b.z); r[7] = (short)f2bf(b.w);
        return r;
    }
}

template<bool F32>
__device__ inline void st1(void* p, size_t idx, float v) {
    if constexpr (F32) ((float*)p)[idx] = v;
    else               ((u16*)p)[idx]   = f2bf(v);
}

// ---------------------------------------------------------------------------
// Kernel 1: K/V for the 64 proxies.
//   Kp[p][d] (natural, bf16), VT[d][p] (transposed, bf16) in workspace.
// ---------------------------------------------------------------------------
template<bool F32>
__device__ void prep_kv_impl(
    const void* __restrict__ proxies,
    const void* __restrict__ Wk, const void* __restrict__ bk,
    const void* __restrict__ Wv, const void* __restrict__ bv,
    u16* __restrict__ Kp, u16* __restrict__ VT)
{
    __shared__ float pf[DD];
    const int p = blockIdx.x;
    const int t = threadIdx.x;          // t = output dim d
    pf[t] = lds1<F32>(proxies, p * DD + t);
    __syncthreads();
    float ak = 0.f, av = 0.f;
    for (int c = 0; c < DD / 8; ++c) {
        short8 wk = ld8<F32>(Wk, t * DD + c * 8);
        short8 wv = ld8<F32>(Wv, t * DD + c * 8);
        #pragma unroll
        for (int j = 0; j < 8; ++j) {
            float xv = pf[c * 8 + j];
            ak += xv * bf2f((u16)wk[j]);
            av += xv * bf2f((u16)wv[j]);
        }
    }
    ak += lds1<F32>(bk, t);
    av += lds1<F32>(bv, t);
    Kp[p * DD + t] = f2bf(ak);
    VT[t * PP + p] = f2bf(av);
}

__global__ __launch_bounds__(128) void prep_kv(
    const void* proxies, const void* Wk, const void* bk,
    const void* Wv, const void* bv, u16* Kp, u16* VT)
{
    if (detect_f32(proxies)) prep_kv_impl<true >(proxies, Wk, bk, Wv, bv, Kp, VT);
    else                     prep_kv_impl<false>(proxies, Wk, bk, Wv, bv, Kp, VT);
}

// ---------------------------------------------------------------------------
// Kernel 2: fully fused per-sample-tile pipeline.
// Block = 256 threads (4 waves), 16 samples per block, grid = 256 blocks.
//   Fragment layouts (HW-verified, guide §3):
//     A: A[m=lane&15][k=quad*8+j], B: B[k=quad*8+j][n=lane&15] (row of W)
//     C/D: col=lane&15, row=quad*4+reg
// ---------------------------------------------------------------------------
template<bool F32>
__device__ void fused_impl(
    const void* __restrict__ x,
    const void* __restrict__ Wq, const void* __restrict__ bq,
    const void* __restrict__ Wo, const void* __restrict__ bo,
    const void* __restrict__ Wfc, const void* __restrict__ bfc,
    const u16* __restrict__ Kp, const u16* __restrict__ VT,
    void* __restrict__ d_out)
{
    __shared__ __attribute__((aligned(16))) u16 q_lds[16][136];
    __shared__ __attribute__((aligned(16))) float sc_lds[NH][16][68];
    __shared__ __attribute__((aligned(16))) u16 al_lds[NH][16][72];
    __shared__ __attribute__((aligned(16))) u16 ag_lds[16][136];
    __shared__ __attribute__((aligned(16))) u16 h_lds[16][136];

    const int tid  = threadIdx.x;
    const int wave = tid >> 6;        // 0..3
    const int lane = tid & 63;
    const int lm   = lane & 15;       // m (A) or n (B/C col) index
    const int quad = lane >> 4;       // 0..3
    const int s0   = blockIdx.x * 16; // sample tile base

    // ---- Phase 1: Q = X @ Wq^T + bq. Wave w covers cols [32w, 32w+32). ----
    {
        float4v acc[2] = {{0,0,0,0},{0,0,0,0}};
        #pragma unroll
        for (int kt = 0; kt < 4; ++kt) {
            short8 a = ld8<F32>(x, (s0 + lm) * DD + kt * 32 + quad * 8);
            #pragma unroll
            for (int nt = 0; nt < 2; ++nt) {
                int d = (2 * wave + nt) * 16 + lm;
                short8 b = ld8<F32>(Wq, d * DD + kt * 32 + quad * 8);
                acc[nt] = __builtin_amdgcn_mfma_f32_16x16x32_bf16(a, b, acc[nt], 0, 0, 0);
            }
        }
        #pragma unroll
        for (int nt = 0; nt < 2; ++nt) {
            int col = (2 * wave + nt) * 16 + lm;
            float bias = lds1<F32>(bq, col);
            #pragma unroll
            for (int r = 0; r < 4; ++r)
                q_lds[quad * 4 + r][col] = f2bf(acc[nt][r] + bias);
        }
    }
    __syncthreads();

    // ---- Phase 2: scores[h][s][p] = (Q_h . K_h) / 8. ----
    const int head = wave >> 1;
    const int wh   = wave & 1;
    {
        float4v acc[2] = {{0,0,0,0},{0,0,0,0}};
        #pragma unroll
        for (int kt = 0; kt < 2; ++kt) {
            short8 a = *(const short8*)(&q_lds[lm][head * HDIM + kt * 32 + quad * 8]);
            #pragma unroll
            for (int nt = 0; nt < 2; ++nt) {
                int p = (wh * 2 + nt) * 16 + lm;
                short8 b = *(const short8*)(Kp + p * DD + head * HDIM + kt * 32 + quad * 8);
                acc[nt] = __builtin_amdgcn_mfma_f32_16x16x32_bf16(a, b, acc[nt], 0, 0, 0);
            }
        }
        const float scale = 0.125f;  // 1/sqrt(64)
        #pragma unroll
        for (int nt = 0; nt < 2; ++nt) {
            int p = (wh * 2 + nt) * 16 + lm;
            #pragma unroll
            for (int r = 0; r < 4; ++r)
                sc_lds[head][quad * 4 + r][p] = acc[nt][r] * scale;
        }
    }
    __syncthreads();

    // ---- Phase 3: softmax over 64 proxies, per (sample, head). 32 rows. ----
    if (tid < 32) {
        int s = tid & 15, hh = tid >> 4;
        float m = -1e30f;
        for (int p = 0; p < PP; ++p) m = fmaxf(m, sc_lds[hh][s][p]);
        float sum = 0.f;
        for (int p = 0; p < PP; ++p) {
            float e = __expf(sc_lds[hh][s][p] - m);
            sum += e;
            sc_lds[hh][s][p] = e;
        }
        float inv = 1.f / sum;
        for (int p = 0; p < PP; ++p)
            al_lds[hh][s][p] = f2bf(sc_lds[hh][s][p] * inv);
    }
    __syncthreads();

    // ---- Phase 4: agg_h = alpha_h[16,64] @ V_h[64,64] (B rows from VT). ----
    {
        float4v acc[2] = {{0,0,0,0},{0,0,0,0}};
        #pragma unroll
        for (int kt = 0; kt < 2; ++kt) {
            short8 a = *(const short8*)(&al_lds[head][lm][kt * 32 + quad * 8]);
            #pragma unroll
            for (int nt = 0; nt < 2; ++nt) {
                int hd = (wh * 2 + nt) * 16 + lm;   // dim within head
                short8 b = *(const short8*)(VT + (head * HDIM + hd) * PP + kt * 32 + quad * 8);
                acc[nt] = __builtin_amdgcn_mfma_f32_16x16x32_bf16(a, b, acc[nt], 0, 0, 0);
            }
        }
        #pragma unroll
        for (int nt = 0; nt < 2; ++nt) {
            int col = head * HDIM + (wh * 2 + nt) * 16 + lm;
            #pragma unroll
            for (int r = 0; r < 4; ++r)
                ag_lds[quad * 4 + r][col] = f2bf(acc[nt][r]);
        }
    }
    __syncthreads();

    // ---- Phase 5: h = relu(agg @ Wo^T + bo); store to LDS + global. ----
    {
        float4v acc[2] = {{0,0,0,0},{0,0,0,0}};
        #pragma unroll
        for (int kt = 0; kt < 4; ++kt) {
            short8 a = *(const short8*)(&ag_lds[lm][kt * 32 + quad * 8]);
            #pragma unroll
            for (int nt = 0; nt < 2; ++nt) {
                int d = (2 * wave + nt) * 16 + lm;
                short8 b = ld8<F32>(Wo, d * DD + kt * 32 + quad * 8);
                acc[nt] = __builtin_amdgcn_mfma_f32_16x16x32_bf16(a, b, acc[nt], 0, 0, 0);
            }
        }
        #pragma unroll
        for (int nt = 0; nt < 2; ++nt) {
            int col = (2 * wave + nt) * 16 + lm;
            float bias = lds1<F32>(bo, col);
            #pragma unroll
            for (int r = 0; r < 4; ++r) {
                int row = quad * 4 + r;
                float hv = fmaxf(acc[nt][r] + bias, 0.f);
                h_lds[row][col] = f2bf(hv);
                // out_h = second output, element offset SS*DD into d_out
                st1<F32>(d_out, (size_t)SS * DD + (size_t)(s0 + row) * DD + col, hv);
            }
        }
    }
    __syncthreads();

    // ---- Phase 6: preds = h @ Wfc^T + bfc. ----
    {
        float4v acc[2] = {{0,0,0,0},{0,0,0,0}};
        #pragma unroll
        for (int kt = 0; kt < 4; ++kt) {
            short8 a = *(const short8*)(&h_lds[lm][kt * 32 + quad * 8]);
            #pragma unroll
            for (int nt = 0; nt < 2; ++nt) {
                int d = (2 * wave + nt) * 16 + lm;
                short8 b = ld8<F32>(Wfc, d * DD + kt * 32 + quad * 8);
                acc[nt] = __builtin_amdgcn_mfma_f32_16x16x32_bf16(a, b, acc[nt], 0, 0, 0);
            }
        }
        #pragma unroll
        for (int nt = 0; nt < 2; ++nt) {
            int col = (2 * wave + nt) * 16 + lm;
            float bias = lds1<F32>(bfc, col);
            #pragma unroll
            for (int r = 0; r < 4; ++r) {
                int row = quad * 4 + r;
                st1<F32>(d_out, (size_t)(s0 + row) * DD + col, acc[nt][r] + bias);
            }
        }
    }
}

__global__ __launch_bounds__(256) void fused_gnn(
    const void* x,
    const void* Wq, const void* bq,
    const void* Wo, const void* bo,
    const void* Wfc, const void* bfc,
    const u16* Kp, const u16* VT,
    void* d_out)
{
    if (detect_f32(x)) fused_impl<true >(x, Wq, bq, Wo, bo, Wfc, bfc, Kp, VT, d_out);
    else               fused_impl<false>(x, Wq, bq, Wo, bo, Wfc, bfc, Kp, VT, d_out);
}

// ---------------------------------------------------------------------------
extern "C" void kernel_launch(void* const* d_in, const int* in_sizes, int n_in,
                              void* d_out, int out_size, void* d_ws, size_t ws_size,
                              hipStream_t stream) {
    const void* x    = d_in[0];
    const void* prox = d_in[1];
    const void* Wq   = d_in[2];
    const void* bq   = d_in[3];
    const void* Wk   = d_in[4];
    const void* bk   = d_in[5];
    const void* Wv   = d_in[6];
    const void* bv   = d_in[7];
    const void* Wo   = d_in[8];
    const void* bo   = d_in[9];
    const void* Wfc  = d_in[10];
    const void* bfc  = d_in[11];
    // d_in[12] = edge_index: dense bipartite, structure known statically -> unused.

    u16* Kp = (u16*)d_ws;            // [P][D] bf16, 16 KB
    u16* VT = Kp + PP * DD;          // [D][P] bf16, 16 KB

    prep_kv<<<PP, DD, 0, stream>>>(prox, Wk, bk, Wv, bv, Kp, VT);
    fused_gnn<<<SS / 16, 256, 0, stream>>>(x, Wq, bq, Wo, bo, Wfc, bfc,
                                           Kp, VT, d_out);
}

// Round 3
// 96.132 us; speedup vs baseline: 1.0194x; 1.0194x over previous
//
#include <hip/hip_runtime.h>
#include <hip/hip_bf16.h>

// Problem constants (from reference)
#define SS 4096   // num_samples
#define DD 128    // embed_dim
#define PP 64     // num_proxies
#define NH 2      // heads
#define HDIM 64   // head dim

typedef unsigned short u16;
typedef __attribute__((ext_vector_type(8))) short short8;   // 8 bf16 in 4 VGPRs
typedef __attribute__((ext_vector_type(4))) float float4v;  // MFMA accumulator

__device__ inline float bf2f(u16 u) {
    union { unsigned int i; float f; } v; v.i = ((unsigned int)u) << 16; return v.f;
}
__device__ inline u16 f2bf(float f) {
    union { float f; unsigned int i; } v; v.f = f;
    unsigned int i = v.i;
    return (u16)((i + 0x7fffu + ((i >> 16) & 1u)) >> 16);  // RNE
}

// ---------------------------------------------------------------------------
// Runtime input-dtype detection (wave-uniform, deterministic).
// fp32 data read as u16 pairs: low half-words have uniform-random exponent
// fields -> ~25% of words have bf16-exponent >= 0xBF (|v| >= 2^64).
// True bf16 N(0,1)-scale tensors never do. 256 words -> miss prob ~1e-16.
// ---------------------------------------------------------------------------
__device__ inline bool detect_f32(const void* raw) {
    const u16* w = (const u16*)raw;
    const int lane = threadIdx.x & 63;
    bool hit = false;
    #pragma unroll
    for (int j = 0; j < 4; ++j) {
        u16 x = w[lane * 4 + j];
        int e = (x >> 7) & 0xFF;
        hit |= (e >= 0xBF);
    }
    return __ballot(hit) != 0ull;
}

// dtype-generic loads/stores -------------------------------------------------
template<bool F32>
__device__ inline float lds1(const void* p, int idx) {
    if constexpr (F32) return ((const float*)p)[idx];
    else               return bf2f(((const u16*)p)[idx]);
}

template<bool F32>
__device__ inline short8 ld8(const void* p, int idx) {  // 8 consecutive elems -> bf16 frag
    if constexpr (!F32) {
        return *(const short8*)((const u16*)p + idx);
    } else {
        const float* f = (const float*)p + idx;
        float4 a = *(const float4*)f;
        float4 b = *(const float4*)(f + 4);
        short8 r;
        r[0] = (short)f2bf(a.x); r[1] = (short)f2bf(a.y);
        r[2] = (short)f2bf(a.z); r[3] = (short)f2bf(a.w);
        r[4] = (short)f2bf(b.x); r[5] = (short)f2bf(b.y);
        r[6] = (short)f2bf(b.z); r[7] = (short)f2bf(b.w);
        return r;
    }
}

template<bool F32>
__device__ inline void st1(void* p, size_t idx, float v) {
    if constexpr (F32) ((float*)p)[idx] = v;
    else               ((u16*)p)[idx]   = f2bf(v);
}

// ---------------------------------------------------------------------------
// SINGLE fused kernel. Block = 256 threads (4 waves), 16 samples per block,
// grid = 256 blocks (1 block/CU). Every block redundantly computes proxy K/V
// via MFMA (64 MFMA/wave, ~hidden) into LDS, eliminating the separate prep
// kernel + its global round-trip + the dependent-launch stall.
//   Fragment layouts (HW-verified, guide §3):
//     A: A[m=lane&15][k=quad*8+j], B: B[k=quad*8+j][n=lane&15] (row of W)
//     C/D: col=lane&15, row=quad*4+reg
// ---------------------------------------------------------------------------
template<bool F32>
__device__ void fused_impl(
    const void* __restrict__ x,    const void* __restrict__ proxies,
    const void* __restrict__ Wq,  const void* __restrict__ bq,
    const void* __restrict__ Wk,  const void* __restrict__ bk,
    const void* __restrict__ Wv,  const void* __restrict__ bv,
    const void* __restrict__ Wo,  const void* __restrict__ bo,
    const void* __restrict__ Wfc, const void* __restrict__ bfc,
    void* __restrict__ d_out)
{
    // LDS: 17408 + 18432 + 4352 + 8704 + 4608 + 4352 + 4352 = 62208 B (<64K)
    __shared__ __attribute__((aligned(16))) u16   K_lds[PP][136];      // K [p][d]
    __shared__ __attribute__((aligned(16))) u16   VT_lds[DD][72];      // V^T [d][p]
    __shared__ __attribute__((aligned(16))) u16   q_lds[16][136];
    __shared__ __attribute__((aligned(16))) float sc_lds[NH][16][68];
    __shared__ __attribute__((aligned(16))) u16   al_lds[NH][16][72];
    __shared__ __attribute__((aligned(16))) u16   ag_lds[16][136];
    __shared__ __attribute__((aligned(16))) u16   h_lds[16][136];

    const int tid  = threadIdx.x;
    const int wave = tid >> 6;        // 0..3
    const int lane = tid & 63;
    const int lm   = lane & 15;       // m (A) or n (B/C col) index
    const int quad = lane >> 4;       // 0..3
    const int s0   = blockIdx.x * 16; // sample tile base

    // ---- Phase 0: K/V for all 64 proxies (redundant per block, MFMA). ----
    // Wave w covers output cols d in [32w, 32w+32) for all 64 proxy rows.
    {
        float4v accK[4][2], accV[4][2];
        #pragma unroll
        for (int rt = 0; rt < 4; ++rt)
            #pragma unroll
            for (int ci = 0; ci < 2; ++ci) {
                accK[rt][ci] = (float4v){0,0,0,0};
                accV[rt][ci] = (float4v){0,0,0,0};
            }
        #pragma unroll
        for (int kt = 0; kt < 4; ++kt) {
            short8 a[4];
            #pragma unroll
            for (int rt = 0; rt < 4; ++rt)
                a[rt] = ld8<F32>(proxies, (rt * 16 + lm) * DD + kt * 32 + quad * 8);
            #pragma unroll
            for (int ci = 0; ci < 2; ++ci) {
                int d = (2 * wave + ci) * 16 + lm;
                short8 bK = ld8<F32>(Wk, d * DD + kt * 32 + quad * 8);
                short8 bV = ld8<F32>(Wv, d * DD + kt * 32 + quad * 8);
                #pragma unroll
                for (int rt = 0; rt < 4; ++rt) {
                    accK[rt][ci] = __builtin_amdgcn_mfma_f32_16x16x32_bf16(a[rt], bK, accK[rt][ci], 0, 0, 0);
                    accV[rt][ci] = __builtin_amdgcn_mfma_f32_16x16x32_bf16(a[rt], bV, accV[rt][ci], 0, 0, 0);
                }
            }
        }
        #pragma unroll
        for (int ci = 0; ci < 2; ++ci) {
            int d = (2 * wave + ci) * 16 + lm;
            float bkv = lds1<F32>(bk, d);
            float bvv = lds1<F32>(bv, d);
            #pragma unroll
            for (int rt = 0; rt < 4; ++rt)
                #pragma unroll
                for (int r = 0; r < 4; ++r) {
                    int p = rt * 16 + quad * 4 + r;
                    K_lds[p][d]  = f2bf(accK[rt][ci][r] + bkv);
                    VT_lds[d][p] = f2bf(accV[rt][ci][r] + bvv);
                }
        }
    }

    // ---- Phase 1: Q = X @ Wq^T + bq (independent of phase 0, same barrier). 
    {
        float4v acc[2] = {{0,0,0,0},{0,0,0,0}};
        #pragma unroll
        for (int kt = 0; kt < 4; ++kt) {
            short8 a = ld8<F32>(x, (s0 + lm) * DD + kt * 32 + quad * 8);
            #pragma unroll
            for (int nt = 0; nt < 2; ++nt) {
                int d = (2 * wave + nt) * 16 + lm;
                short8 b = ld8<F32>(Wq, d * DD + kt * 32 + quad * 8);
                acc[nt] = __builtin_amdgcn_mfma_f32_16x16x32_bf16(a, b, acc[nt], 0, 0, 0);
            }
        }
        #pragma unroll
        for (int nt = 0; nt < 2; ++nt) {
            int col = (2 * wave + nt) * 16 + lm;
            float bias = lds1<F32>(bq, col);
            #pragma unroll
            for (int r = 0; r < 4; ++r)
                q_lds[quad * 4 + r][col] = f2bf(acc[nt][r] + bias);
        }
    }
    __syncthreads();

    // ---- Phase 2: scores[h][s][p] = (Q_h . K_h) / 8. ----
    const int head = wave >> 1;
    const int wh   = wave & 1;
    {
        float4v acc[2] = {{0,0,0,0},{0,0,0,0}};
        #pragma unroll
        for (int kt = 0; kt < 2; ++kt) {
            short8 a = *(const short8*)(&q_lds[lm][head * HDIM + kt * 32 + quad * 8]);
            #pragma unroll
            for (int nt = 0; nt < 2; ++nt) {
                int p = (wh * 2 + nt) * 16 + lm;
                short8 b = *(const short8*)(&K_lds[p][head * HDIM + kt * 32 + quad * 8]);
                acc[nt] = __builtin_amdgcn_mfma_f32_16x16x32_bf16(a, b, acc[nt], 0, 0, 0);
            }
        }
        const float scale = 0.125f;  // 1/sqrt(64)
        #pragma unroll
        for (int nt = 0; nt < 2; ++nt) {
            int p = (wh * 2 + nt) * 16 + lm;
            #pragma unroll
            for (int r = 0; r < 4; ++r)
                sc_lds[head][quad * 4 + r][p] = acc[nt][r] * scale;
        }
    }
    __syncthreads();

    // ---- Phase 3: softmax over 64 proxies, per (sample, head). ----
    // Wave 0 only: 64 lanes, each handles half a (s,h) row; halves combine
    // via shfl_xor(.,32) within the wave.
    if (tid < 64) {
        int s = tid & 15, hh = (tid >> 4) & 1, half = tid >> 5;
        const float* row = &sc_lds[hh][s][0];
        float m = -1e30f;
        #pragma unroll
        for (int j = 0; j < 32; ++j) m = fmaxf(m, row[half * 32 + j]);
        m = fmaxf(m, __shfl_xor(m, 32));
        float e[32], sum = 0.f;
        #pragma unroll
        for (int j = 0; j < 32; ++j) {
            e[j] = __expf(row[half * 32 + j] - m);
            sum += e[j];
        }
        sum += __shfl_xor(sum, 32);
        float inv = 1.f / sum;
        #pragma unroll
        for (int j = 0; j < 32; ++j)
            al_lds[hh][s][half * 32 + j] = f2bf(e[j] * inv);
    }
    __syncthreads();

    // ---- Phase 4: agg_h = alpha_h[16,64] @ V_h[64,64] (B rows from VT). ----
    {
        float4v acc[2] = {{0,0,0,0},{0,0,0,0}};
        #pragma unroll
        for (int kt = 0; kt < 2; ++kt) {
            short8 a = *(const short8*)(&al_lds[head][lm][kt * 32 + quad * 8]);
            #pragma unroll
            for (int nt = 0; nt < 2; ++nt) {
                int hd = (wh * 2 + nt) * 16 + lm;   // dim within head
                short8 b = *(const short8*)(&VT_lds[head * HDIM + hd][kt * 32 + quad * 8]);
                acc[nt] = __builtin_amdgcn_mfma_f32_16x16x32_bf16(a, b, acc[nt], 0, 0, 0);
            }
        }
        #pragma unroll
        for (int nt = 0; nt < 2; ++nt) {
            int col = head * HDIM + (wh * 2 + nt) * 16 + lm;
            #pragma unroll
            for (int r = 0; r < 4; ++r)
                ag_lds[quad * 4 + r][col] = f2bf(acc[nt][r]);
        }
    }
    __syncthreads();

    // ---- Phase 5: h = relu(agg @ Wo^T + bo); store to LDS + global. ----
    {
        float4v acc[2] = {{0,0,0,0},{0,0,0,0}};
        #pragma unroll
        for (int kt = 0; kt < 4; ++kt) {
            short8 a = *(const short8*)(&ag_lds[lm][kt * 32 + quad * 8]);
            #pragma unroll
            for (int nt = 0; nt < 2; ++nt) {
                int d = (2 * wave + nt) * 16 + lm;
                short8 b = ld8<F32>(Wo, d * DD + kt * 32 + quad * 8);
                acc[nt] = __builtin_amdgcn_mfma_f32_16x16x32_bf16(a, b, acc[nt], 0, 0, 0);
            }
        }
        #pragma unroll
        for (int nt = 0; nt < 2; ++nt) {
            int col = (2 * wave + nt) * 16 + lm;
            float bias = lds1<F32>(bo, col);
            #pragma unroll
            for (int r = 0; r < 4; ++r) {
                int row = quad * 4 + r;
                float hv = fmaxf(acc[nt][r] + bias, 0.f);
                h_lds[row][col] = f2bf(hv);
                // out_h = second output, element offset SS*DD into d_out
                st1<F32>(d_out, (size_t)SS * DD + (size_t)(s0 + row) * DD + col, hv);
            }
        }
    }
    __syncthreads();

    // ---- Phase 6: preds = h @ Wfc^T + bfc. ----
    {
        float4v acc[2] = {{0,0,0,0},{0,0,0,0}};
        #pragma unroll
        for (int kt = 0; kt < 4; ++kt) {
            short8 a = *(const short8*)(&h_lds[lm][kt * 32 + quad * 8]);
            #pragma unroll
            for (int nt = 0; nt < 2; ++nt) {
                int d = (2 * wave + nt) * 16 + lm;
                short8 b = ld8<F32>(Wfc, d * DD + kt * 32 + quad * 8);
                acc[nt] = __builtin_amdgcn_mfma_f32_16x16x32_bf16(a, b, acc[nt], 0, 0, 0);
            }
        }
        #pragma unroll
        for (int nt = 0; nt < 2; ++nt) {
            int col = (2 * wave + nt) * 16 + lm;
            float bias = lds1<F32>(bfc, col);
            #pragma unroll
            for (int r = 0; r < 4; ++r) {
                int row = quad * 4 + r;
                st1<F32>(d_out, (size_t)(s0 + row) * DD + col, acc[nt][r] + bias);
            }
        }
    }
}

__global__ __launch_bounds__(256) void fused_gnn(
    const void* x,   const void* proxies,
    const void* Wq,  const void* bq,
    const void* Wk,  const void* bk,
    const void* Wv,  const void* bv,
    const void* Wo,  const void* bo,
    const void* Wfc, const void* bfc,
    void* d_out)
{
    if (detect_f32(x))
        fused_impl<true >(x, proxies, Wq, bq, Wk, bk, Wv, bv, Wo, bo, Wfc, bfc, d_out);
    else
        fused_impl<false>(x, proxies, Wq, bq, Wk, bk, Wv, bv, Wo, bo, Wfc, bfc, d_out);
}

// ---------------------------------------------------------------------------
extern "C" void kernel_launch(void* const* d_in, const int* in_sizes, int n_in,
                              void* d_out, int out_size, void* d_ws, size_t ws_size,
                              hipStream_t stream) {
    // d_in order: x, proxies, Wq,bq, Wk,bk, Wv,bv, Wo,bo, Wfc,bfc, edge_index
    // edge_index is dense-bipartite by construction -> structure known statically.
    fused_gnn<<<SS / 16, 256, 0, stream>>>(
        d_in[0], d_in[1], d_in[2], d_in[3], d_in[4], d_in[5], d_in[6],
        d_in[7], d_in[8], d_in[9], d_in[10], d_in[11], d_out);
}